// Round 15
// baseline (487.386 us; speedup 1.0000x reference)
//
#include <hip/hip_runtime.h>
#include <math.h>

#define B_  32
#define N_  256
#define D_  1024
#define H_  16
#define E_  512
#define ED_ 256
#define HD_ 64
#define QS_ 3072                  // merged qkv row stride
#define NEG_ (-3.4028234663852886e38f)

typedef __attribute__((ext_vector_type(8))) short short8;
typedef __attribute__((ext_vector_type(4))) float f32x4;
typedef __attribute__((ext_vector_type(16))) float f32x16;
typedef unsigned short ushort_t;
typedef unsigned int uint_t;

union U16x8 { uint4 u4; ushort_t s[8]; };

static __device__ __forceinline__ ushort_t f2bf(float f) {
    uint_t u = __builtin_bit_cast(uint_t, f);
    u = (u + 0x7fff + ((u >> 16) & 1)) >> 16;
    return (ushort_t)u;
}

// async global->LDS, 16 bytes per lane (m97 pattern)
static __device__ __forceinline__ void gload_lds16(const void* g, void* l) {
    __builtin_amdgcn_global_load_lds(
        (const __attribute__((address_space(1))) unsigned int*)g,
        (__attribute__((address_space(3))) unsigned int*)l, 16, 0, 0);
}

// ---------------- LayerNorm: fp32 in -> bf16 out -----------------------------
__global__ __launch_bounds__(256) void ln_bf16_kernel(const float* __restrict__ x,
                                                      const float* __restrict__ g,
                                                      const float* __restrict__ b,
                                                      ushort_t* __restrict__ out) {
    int row = blockIdx.x;
    const float* xr = x + (size_t)row * D_;
    ushort_t* yr = out + (size_t)row * D_;
    __shared__ float red[256];
    int t = threadIdx.x;
    float vals[4];
    float s = 0.f;
#pragma unroll
    for (int i = 0; i < 4; ++i) { vals[i] = xr[t + i * 256]; s += vals[i]; }
    red[t] = s; __syncthreads();
    for (int off = 128; off > 0; off >>= 1) { if (t < off) red[t] += red[t + off]; __syncthreads(); }
    float mean = red[0] * (1.f / D_);
    __syncthreads();
    float vs = 0.f;
#pragma unroll
    for (int i = 0; i < 4; ++i) { float d = vals[i] - mean; vs += d * d; }
    red[t] = vs; __syncthreads();
    for (int off = 128; off > 0; off >>= 1) { if (t < off) red[t] += red[t + off]; __syncthreads(); }
    float rstd = 1.f / sqrtf(red[0] * (1.f / D_) + 1e-5f);
#pragma unroll
    for (int i = 0; i < 4; ++i) {
        int c = t + i * 256;
        yr[c] = f2bf((vals[i] - mean) * rstd * g[c] + b[c]);
    }
}

// ---------------- fused prep: all weight transposes + concat bias ------------
__global__ __launch_bounds__(256) void prep_kernel(
    const float* __restrict__ Wq, const float* __restrict__ Wk,
    const float* __restrict__ Wv, const float* __restrict__ Wo,
    const float* __restrict__ W1, const float* __restrict__ W2,
    const float* __restrict__ bq, const float* __restrict__ bk,
    const float* __restrict__ bv,
    ushort_t* __restrict__ qkvT, ushort_t* __restrict__ WoT,
    ushort_t* __restrict__ W1T, ushort_t* __restrict__ W2T,
    float* __restrict__ cb)
{
    int id = blockIdx.x;
    if (id >= 12288) {
        int i = (id - 12288) * 256 + threadIdx.x;
        cb[i] = (i < 1024) ? bq[i] : ((i < 2048) ? bk[i - 1024] : bv[i - 2048]);
        return;
    }
    const float* in; ushort_t* outp; int K, N, tid;
    if (id < 4096) {
        int wsel = id >> 10; tid = id & 1023; K = D_; N = D_;
        in   = (wsel == 0) ? Wq : (wsel == 1) ? Wk : (wsel == 2) ? Wv : Wo;
        outp = (wsel == 0) ? qkvT : (wsel == 1) ? qkvT + 1024 * 1024
             : (wsel == 2) ? qkvT + 2 * 1024 * 1024 : WoT;
    } else if (id < 8192) { tid = id - 4096; K = D_; N = 4 * D_; in = W1; outp = W1T; }
    else                  { tid = id - 8192; K = 4 * D_; N = D_; in = W2; outp = W2T; }
    int tilesX = N >> 5;
    int n0 = (tid % tilesX) * 32, k0 = (tid / tilesX) * 32;

    __shared__ float tile[32][33];
    int tx = threadIdx.x & 31, ty = threadIdx.x >> 5;   // ty 0..7
#pragma unroll
    for (int r = 0; r < 4; ++r)
        tile[ty + r * 8][tx] = in[(size_t)(k0 + ty + r * 8) * N + n0 + tx];
    __syncthreads();
#pragma unroll
    for (int r = 0; r < 4; ++r)
        outp[(size_t)(n0 + ty + r * 8) * K + k0 + tx] = f2bf(tile[tx][ty + r * 8]);
}

// ---------------- edge-bias projection: eb[b,e,h] ----------------------------
__global__ __launch_bounds__(256) void eb_kernel(const float* __restrict__ re,
                                                 const float* __restrict__ We,
                                                 const float* __restrict__ be,
                                                 float* __restrict__ eb) {
    __shared__ float rs[16 * 256];
    __shared__ float wl[256 * 16];
    int t = threadIdx.x;
    int be0 = blockIdx.x * 16;     // base (b*E+e)
#pragma unroll
    for (int i = 0; i < 16; ++i) wl[t + i * 256] = We[t + i * 256];
#pragma unroll
    for (int i = 0; i < 16; ++i) rs[t + i * 256] = re[(size_t)be0 * 256 + t + i * 256];
    __syncthreads();
    int el = t >> 4, h = t & 15;
    float s = be[h];
#pragma unroll 8
    for (int i = 0; i < 256; ++i) s += rs[el * 256 + i] * wl[i * 16 + h];
    eb[(size_t)(be0 + el) * 16 + h] = s;
}

// ---------------- edge scatter: last-writer-wins priority table --------------
__global__ void scatter_kernel(const int* __restrict__ edges, const float* __restrict__ emask,
                               int* __restrict__ prio) {
    int idx = blockIdx.x * blockDim.x + threadIdx.x;   // b*E + e
    if (idx >= B_ * E_) return;
    if (emask[idx] == 0.f) return;
    int b = idx / E_, e = idx % E_;
    int s = edges[2 * idx], d = edges[2 * idx + 1];
    s = min(max(s, 0), N_ - 1);
    d = min(max(d, 0), N_ - 1);
    int* base = prio + (size_t)b * N_ * N_;
    atomicMax(&base[s * N_ + d], e);
    atomicMax(&base[d * N_ + s], e + E_);
}

// ---------------- bf16 MFMA GEMM, BK=128 (modes 1,3 — grid-capped) -----------
template<int MODE>
__global__ __launch_bounds__(256) void gemm_res(
    const ushort_t* __restrict__ A, const ushort_t* __restrict__ BT,
    const float* __restrict__ bias, const float* __restrict__ res,
    const float* __restrict__ nm, void* __restrict__ Cout,
    int M, int N, int K)
{
    __shared__ ushort_t As[2][128 * 64];   // 32 KB
    __shared__ ushort_t Bs[2][128 * 64];   // 32 KB
    int t = threadIdx.x;
    int lane = t & 63;
    int l31 = lane & 31, lh = lane >> 5;
    int w = t >> 6;
    int wr = (w >> 1) * 64, wc = (w & 1) * 64;

    int bid = blockIdx.x;
    int xcd = bid & 7;
    int lid = bid >> 3;
    int st  = lid >> 5;
    int ls  = lid & 31;
    int brow = xcd * 8 + (ls >> 2);
    int bcol = st * 4 + (ls & 3);
    int row0 = brow * 128, col0 = bcol * 128;

    const ushort_t* Ag = A + (size_t)row0 * K;
    const ushort_t* Bg = BT + (size_t)col0 * K;
    int srow = t >> 3;
    int slot = t & 7;
    int sc = (slot ^ (srow & 7)) * 8;

    f32x16 acc[2][2];
#pragma unroll
    for (int i = 0; i < 2; ++i)
#pragma unroll
        for (int j = 0; j < 2; ++j)
#pragma unroll
            for (int r = 0; r < 16; ++r) acc[i][j][r] = 0.f;

    for (int k0 = 0; k0 < K; k0 += 128) {
#pragma unroll
        for (int p = 0; p < 2; ++p)
#pragma unroll
            for (int i = 0; i < 4; ++i) {
                gload_lds16(Ag + (size_t)(i * 32 + srow) * K + k0 + p * 64 + sc,
                            (char*)As + p * 16384 + i * 4096 + t * 16);
                gload_lds16(Bg + (size_t)(i * 32 + srow) * K + k0 + p * 64 + sc,
                            (char*)Bs + p * 16384 + i * 4096 + t * 16);
            }
        __syncthreads();
#pragma unroll
        for (int ks8 = 0; ks8 < 8; ++ks8) {
            const char* Ab = (const char*)As + (ks8 >> 2) * 16384;
            const char* Bb = (const char*)Bs + (ks8 >> 2) * 16384;
            int kk = ks8 & 3;
            short8 af[2], bfr[2];
#pragma unroll
            for (int it = 0; it < 2; ++it) {
                int m = wr + it * 32 + l31;
                int x = ((kk * 2 + lh) ^ (m & 7)) * 16;
                af[it] = *(const short8*)(Ab + m * 128 + x);
            }
#pragma unroll
            for (int jt = 0; jt < 2; ++jt) {
                int n = wc + jt * 32 + l31;
                int x = ((kk * 2 + lh) ^ (n & 7)) * 16;
                bfr[jt] = *(const short8*)(Bb + n * 128 + x);
            }
#pragma unroll
            for (int it = 0; it < 2; ++it)
#pragma unroll
                for (int jt = 0; jt < 2; ++jt)
                    acc[it][jt] = __builtin_amdgcn_mfma_f32_32x32x16_bf16(af[it], bfr[jt], acc[it][jt], 0, 0, 0);
        }
        __syncthreads();
    }

#pragma unroll
    for (int it = 0; it < 2; ++it) {
#pragma unroll
        for (int jt = 0; jt < 2; ++jt) {
            int col = col0 + wc + jt * 32 + l31;
            float bcol_b = bias[col];
#pragma unroll
            for (int reg = 0; reg < 16; ++reg) {
                int row = row0 + wr + it * 32 + (reg & 3) + 8 * (reg >> 2) + 4 * lh;
                float v = acc[it][jt][reg] + bcol_b;
                if (MODE == 1) {
                    ((float*)Cout)[(size_t)row * N + col] = v + res[(size_t)row * N + col];
                } else { // 3
                    v = (v + res[(size_t)row * N + col]) * nm[row];
                    ((float*)Cout)[(size_t)row * N + col] = v;
                }
            }
        }
    }
}

// ---------------- 256x256 8-phase GEMM (modes 0,2; m201 stagger) -------------
// MODE 0: +bias -> bf16   MODE 2: silu(+bias) -> bf16
// decode: 8 XCDs x (grid/8) blocks; brow = xcd*4 + (lid&3) in 0..31, bcol =
// lid>>2. Bijective for grid 384 (N=3072) and 512 (N=4096).
template<int MODE, int NBN>
__global__ __launch_bounds__(512) void gemm256(
    const ushort_t* __restrict__ A, const ushort_t* __restrict__ BT,
    const float* __restrict__ bias, ushort_t* __restrict__ Cout,
    int M, int N, int K)
{
    __shared__ ushort_t As[2][2][128 * 64];   // 64 KB
    __shared__ ushort_t Bs[2][2][128 * 64];   // 64 KB

    int t = threadIdx.x;
    int lane = t & 63;
    int w = t >> 6;                 // 0..7
    int wm = w >> 2, wn = w & 3;    // 2M x 4N
    int c2 = lane & 15, quad = lane >> 4;

    int bid = blockIdx.x;
    int xcd = bid & 7, lid = bid >> 3;
    int brow = xcd * 4 + (lid & 3);             // brow fastest within XCD
    int bcol = lid >> 2;
    int row0 = brow * 256, col0 = bcol * 256;

    const ushort_t* Ag = A + (size_t)row0 * K;
    const ushort_t* Bg = BT + (size_t)col0 * K;

    int srow = t >> 3, slot = t & 7;            // srow 0..63
    int sc = (slot ^ (srow & 7)) * 8;           // source chunk (elems)

    // hh: 0=A half0, 1=A half1, 2=B half0, 3=B half1 ; one half = 2 gloads
    auto stage = [&](int buf, int hh, int kt) {
        const ushort_t* g = (hh < 2) ? Ag : Bg;
        int h = hh & 1;
        char* l = (hh < 2) ? (char*)&As[buf][h][0] : (char*)&Bs[buf][h][0];
        gload_lds16(g + (size_t)(h * 128 + srow) * K + kt * 64 + sc, l + t * 16);
        gload_lds16(g + (size_t)(h * 128 + 64 + srow) * K + kt * 64 + sc, l + 8192 + t * 16);
    };

    f32x4 acc[8][4];
#pragma unroll
    for (int a_ = 0; a_ < 8; ++a_)
#pragma unroll
        for (int b_ = 0; b_ < 4; ++b_)
#pragma unroll
            for (int r = 0; r < 4; ++r) acc[a_][b_][r] = 0.f;

    int T = K >> 6;
    // prologue: tile0 {A0,A1,B0,B1}, tile1 {B0,B1,A0}  (age order matters)
    stage(0, 0, 0); stage(0, 1, 0); stage(0, 2, 0); stage(0, 3, 0);
    if (T > 1) { stage(1, 2, 1); stage(1, 3, 1); stage(1, 0, 1); }

    const int bhalf = wn >> 1, bco = (wn & 1) * 64;

    for (int tau = 0; tau < T; ++tau) {
        int bc = tau & 1;
        const char* Ab = (const char*)&As[bc][wm][0];
        const char* Bb = (const char*)&Bs[bc][bhalf][0];
        short8 bfr[4][2];
#pragma unroll
        for (int q = 0; q < 4; ++q) {
            if (q == 0) {
                if (tau == T - 1) asm volatile("s_waitcnt vmcnt(0)" ::: "memory");
                else              asm volatile("s_waitcnt vmcnt(6)" ::: "memory");
                __builtin_amdgcn_s_barrier();
                __builtin_amdgcn_sched_barrier(0);
            }
            short8 afr[2][2];
#pragma unroll
            for (int it = 0; it < 2; ++it)
#pragma unroll
                for (int ks = 0; ks < 2; ++ks) {
                    int fr = q * 32 + it * 16 + c2;
                    afr[it][ks] = *(const short8*)(Ab + fr * 128 + (((ks * 4 + quad) ^ (fr & 7)) * 16));
                }
            if (q == 0) {
#pragma unroll
                for (int jt = 0; jt < 4; ++jt)
#pragma unroll
                    for (int ks = 0; ks < 2; ++ks) {
                        int fr = bco + jt * 16 + c2;
                        bfr[jt][ks] = *(const short8*)(Bb + fr * 128 + (((ks * 4 + quad) ^ (fr & 7)) * 16));
                    }
            }
            // staggered staging slot
            if (q == 0) { if (tau + 1 < T) stage(bc ^ 1, 1, tau + 1); }
            else if (tau + 2 < T) stage(bc, (q == 1) ? 2 : (q == 2) ? 3 : 0, tau + 2);

            asm volatile("s_waitcnt lgkmcnt(0)" ::: "memory");
            __builtin_amdgcn_sched_barrier(0);
            __builtin_amdgcn_s_setprio(1);
#pragma unroll
            for (int it = 0; it < 2; ++it)
#pragma unroll
                for (int jt = 0; jt < 4; ++jt) {
                    acc[q * 2 + it][jt] = __builtin_amdgcn_mfma_f32_16x16x32_bf16(
                        afr[it][0], bfr[jt][0], acc[q * 2 + it][jt], 0, 0, 0);
                    acc[q * 2 + it][jt] = __builtin_amdgcn_mfma_f32_16x16x32_bf16(
                        afr[it][1], bfr[jt][1], acc[q * 2 + it][jt], 0, 0, 0);
                }
            __builtin_amdgcn_s_setprio(0);
            __builtin_amdgcn_sched_barrier(0);
            __builtin_amdgcn_s_barrier();
        }
    }

    // epilogue: 16x16 C/D layout (m89): row = quad*4 + r, col = c2
#pragma unroll
    for (int q = 0; q < 4; ++q)
#pragma unroll
        for (int it = 0; it < 2; ++it) {
            int row = row0 + wm * 128 + q * 32 + it * 16 + quad * 4;
#pragma unroll
            for (int jt = 0; jt < 4; ++jt) {
                int col = col0 + wn * 64 + jt * 16 + c2;
                float bc_ = bias[col];
#pragma unroll
                for (int r = 0; r < 4; ++r) {
                    float v = acc[q * 2 + it][jt][r] + bc_;
                    if (MODE == 2) v = v / (1.f + __expf(-v));
                    Cout[(size_t)(row + r) * N + col] = f2bf(v);
                }
            }
        }
}

// ---------------- MFMA attention: block = (b, h, q-tile of 64) ---------------
__global__ __launch_bounds__(256, 2) void attn_mfma_kernel(
    const ushort_t* __restrict__ qkv, const int* __restrict__ prio,
    const float* __restrict__ eb, const float* __restrict__ nm,
    ushort_t* __restrict__ out)
{
    int xb = blockIdx.x;
    int bid = (xb & 7) * 256 + (xb >> 3);
    int h = bid & 15, qt = (bid >> 4) & 3, b = bid >> 6;
    int t = threadIdx.x;

    __shared__ ushort_t Ks[256 * 72];
    __shared__ ushort_t Vt[64 * 264];

    int lane = t & 63, c = lane & 15, quad = lane >> 4;
    int w = t >> 6;
    int qbase = qt * 64 + w * 16 + quad * 4;

    int pr[16][4];
    const int* prp = prio + ((size_t)(b * N_ + qbase)) * N_ + c;
#pragma unroll
    for (int j = 0; j < 16; ++j)
#pragma unroll
        for (int r = 0; r < 4; ++r)
            pr[j][r] = prp[(size_t)r * N_ + j * 16];

    float nmq[4];
#pragma unroll
    for (int r = 0; r < 4; ++r) nmq[r] = nm[b * N_ + qbase + r];
    float nmk[16];
#pragma unroll
    for (int j = 0; j < 16; ++j) nmk[j] = nm[b * N_ + j * 16 + c];

    const ushort_t* qg = qkv + ((size_t)(b * N_ + qt * 64 + w * 16 + c)) * QS_ + h * HD_;
    short8 aq0 = *(const short8*)(const void*)(qg + quad * 8);
    short8 aq1 = *(const short8*)(const void*)(qg + 32 + quad * 8);

    int lr = t >> 3, lc = (t & 7) * 8;
    const ushort_t* kg = qkv + ((size_t)(b * N_)) * QS_ + 1024 + h * HD_;
#pragma unroll
    for (int r = 0; r < 256; r += 32)
        *(uint4*)&Ks[(lr + r) * 72 + lc] = *(const uint4*)&kg[(size_t)(lr + r) * QS_ + lc];
    const ushort_t* vg = qkv + ((size_t)(b * N_)) * QS_ + 2048 + h * HD_;
#pragma unroll
    for (int r = 0; r < 256; r += 32) {
        U16x8 uu; uu.u4 = *(const uint4*)&vg[(size_t)(lr + r) * QS_ + lc];
#pragma unroll
        for (int i = 0; i < 8; ++i)
            Vt[(lc + i) * 264 + lr + r] = uu.s[i];
    }

    const float* ebb = eb + (size_t)b * E_ * H_ + h;
    float badd[16][4];
#pragma unroll
    for (int j = 0; j < 16; ++j) {
        int key = j * 16 + c;
#pragma unroll
        for (int r = 0; r < 4; ++r) {
            int p = pr[j][r];
            float bias = 0.f;
            bool adj = (key == qbase + r);
            if (p >= 0) {
                int e = (p >= E_) ? p - E_ : p;
                bias = ebb[(size_t)e * H_];
                adj = true;
            }
            bool ok = adj && (nmq[r] != 0.f) && (nmk[j] != 0.f);
            badd[j][r] = ok ? bias : -3.0e38f;
        }
    }
    __syncthreads();

    f32x4 z = {0.f, 0.f, 0.f, 0.f};
    f32x4 acc[16];
#pragma unroll
    for (int j = 0; j < 16; ++j) acc[j] = z;
    __builtin_amdgcn_s_setprio(1);
#pragma unroll
    for (int j = 0; j < 16; ++j) {
        short8 b0 = *(const short8*)(const void*)(Ks + (j * 16 + c) * 72 + quad * 8);
        short8 b1 = *(const short8*)(const void*)(Ks + (j * 16 + c) * 72 + 32 + quad * 8);
        acc[j] = __builtin_amdgcn_mfma_f32_16x16x32_bf16(aq0, b0, acc[j], 0, 0, 0);
        acc[j] = __builtin_amdgcn_mfma_f32_16x16x32_bf16(aq1, b1, acc[j], 0, 0, 0);
    }
    __builtin_amdgcn_s_setprio(0);

#pragma unroll
    for (int j = 0; j < 16; ++j)
#pragma unroll
        for (int r = 0; r < 4; ++r)
            acc[j][r] = acc[j][r] * 0.125f + badd[j][r];

    float inv[4];
#pragma unroll
    for (int r = 0; r < 4; ++r) {
        float m = acc[0][r];
#pragma unroll
        for (int j = 1; j < 16; ++j) m = fmaxf(m, acc[j][r]);
        m = fmaxf(m, __shfl_xor(m, 1));
        m = fmaxf(m, __shfl_xor(m, 2));
        m = fmaxf(m, __shfl_xor(m, 4));
        m = fmaxf(m, __shfl_xor(m, 8));
        float s = 0.f;
#pragma unroll
        for (int j = 0; j < 16; ++j) {
            float p = __expf(acc[j][r] - m);
            acc[j][r] = p;
            s += p;
        }
        s += __shfl_xor(s, 1);
        s += __shfl_xor(s, 2);
        s += __shfl_xor(s, 4);
        s += __shfl_xor(s, 8);
        inv[r] = 1.f / s;
    }

    __syncthreads();
    ushort_t* Ps = Ks;
#pragma unroll
    for (int j = 0; j < 16; ++j)
#pragma unroll
        for (int r = 0; r < 4; ++r)
            Ps[(w * 16 + quad * 4 + r) * 264 + j * 16 + c] = f2bf(acc[j][r] * inv[r]);
    asm volatile("s_waitcnt lgkmcnt(0)" ::: "memory");

    f32x4 oc[4];
#pragma unroll
    for (int dt = 0; dt < 4; ++dt) oc[dt] = z;
    __builtin_amdgcn_s_setprio(1);
#pragma unroll
    for (int k0 = 0; k0 < 256; k0 += 32) {
        short8 ap = *(const short8*)(const void*)(Ps + (w * 16 + c) * 264 + k0 + quad * 8);
#pragma unroll
        for (int dt = 0; dt < 4; ++dt) {
            short8 bv = *(const short8*)(const void*)(Vt + (dt * 16 + c) * 264 + k0 + quad * 8);
            oc[dt] = __builtin_amdgcn_mfma_f32_16x16x32_bf16(ap, bv, oc[dt], 0, 0, 0);
        }
    }
    __builtin_amdgcn_s_setprio(0);
    ushort_t* og = out + ((size_t)(b * N_ + qt * 64 + w * 16)) * D_ + h * HD_;
#pragma unroll
    for (int dt = 0; dt < 4; ++dt)
#pragma unroll
        for (int r = 0; r < 4; ++r)
            og[(size_t)(quad * 4 + r) * D_ + dt * 16 + c] = f2bf(oc[dt][r]);
}

extern "C" void kernel_launch(void* const* d_in, const int* in_sizes, int n_in,
                              void* d_out, int out_size, void* d_ws, size_t ws_size,
                              hipStream_t stream) {
    const float* x     = (const float*)d_in[0];
    const float* nm    = (const float*)d_in[1];
    const int*   edges = (const int*)d_in[2];
    const float* emask = (const float*)d_in[3];
    const float* remb  = (const float*)d_in[4];
    const float* ln_g  = (const float*)d_in[5];
    const float* ln_b  = (const float*)d_in[6];
    const float* Wq = (const float*)d_in[7];  const float* bq = (const float*)d_in[8];
    const float* Wk = (const float*)d_in[9];  const float* bk = (const float*)d_in[10];
    const float* Wv = (const float*)d_in[11]; const float* bv = (const float*)d_in[12];
    const float* We = (const float*)d_in[13]; const float* be = (const float*)d_in[14];
    const float* Wo = (const float*)d_in[15]; const float* bo = (const float*)d_in[16];
    const float* ff_g = (const float*)d_in[17]; const float* ff_b = (const float*)d_in[18];
    const float* W1 = (const float*)d_in[19]; const float* b1 = (const float*)d_in[20];
    const float* W2 = (const float*)d_in[21]; const float* b2 = (const float*)d_in[22];
    float* out = (float*)d_out;

    char* ws = (char*)d_ws;
    const size_t MB = 1ll << 20;
    int*      prio = (int*)ws;                       // 0..8 MB
    float*    ebuf = (float*)(ws + 8 * MB);          // 8..9 MB
    ushort_t* xn   = (ushort_t*)(ws + 9 * MB);       // 9..25 MB (reused: attn_out)
    float*    x2   = (float*)(ws + 25 * MB);         // 25..57 MB
    ushort_t* hn   = (ushort_t*)(ws + 57 * MB);      // 57..73 MB
    ushort_t* qkv  = (ushort_t*)(ws + 73 * MB);      // 73..121 MB [8192][3072]
    ushort_t* mid  = qkv;                            // 73..137 MB (qkv dead by then)
    ushort_t* qkvT = (ushort_t*)(ws + 137 * MB);     // 137..143 MB [3072][1024]
    ushort_t* WoT  = (ushort_t*)(ws + 143 * MB);     // 143..145 MB
    ushort_t* W1T  = (ushort_t*)(ws + 145 * MB);     // 145..153 MB [4096][1024]
    ushort_t* W2T  = (ushort_t*)(ws + 153 * MB);     // 153..161 MB [1024][4096]
    float*    cb   = (float*)(ws + 161 * MB);        // 161..161.02 MB [3072]
    ushort_t* aout = xn;

    const int M = B_ * N_;   // 8192

    (void)hipMemsetAsync(prio, 0xFF, (size_t)B_ * N_ * N_ * sizeof(int), stream);
    eb_kernel<<<B_ * E_ / 16, 256, 0, stream>>>(remb, We, be, ebuf);
    scatter_kernel<<<(B_ * E_ + 255) / 256, 256, 0, stream>>>(edges, emask, prio);

    prep_kernel<<<12300, 256, 0, stream>>>(Wq, Wk, Wv, Wo, W1, W2, bq, bk, bv,
                                           qkvT, WoT, W1T, W2T, cb);

    ln_bf16_kernel<<<M, 256, 0, stream>>>(x, ln_g, ln_b, xn);

    // QKV projection: 256x256 8-phase (m201 stagger), grid 384 = 8 XCD x 48
    gemm256<0, 12><<<384, 512, 0, stream>>>(xn, qkvT, cb, qkv, M, QS_, D_);

    attn_mfma_kernel<<<B_ * H_ * 4, 256, 0, stream>>>(qkv, prio, ebuf, nm, aout);

    gemm_res<1><<<8 * 64, 256, 0, stream>>>(aout, WoT, bo, x, nullptr, x2, M, D_, D_);
    ln_bf16_kernel<<<M, 256, 0, stream>>>(x2, ff_g, ff_b, hn);

    // FFN up: 256x256 8-phase (m201 stagger), grid 512 = 2 rounds @ 1 block/CU
    gemm256<2, 16><<<512, 512, 0, stream>>>(hn, W1T, b1, mid, M, 4 * D_, D_);
    // FFN down: BK=128, grid-capped 512 blocks (best measured structure)
    gemm_res<3><<<8 * 64, 256, 0, stream>>>(mid, W2T, b2, x2, nm, out, M, D_, 4 * D_);
}

// Round 16
// 481.745 us; speedup vs baseline: 1.0117x; 1.0117x over previous
//
#include <hip/hip_runtime.h>
#include <math.h>

#define B_  32
#define N_  256
#define D_  1024
#define H_  16
#define E_  512
#define ED_ 256
#define HD_ 64
#define QS_ 3072                  // merged qkv row stride
#define NEG_ (-3.4028234663852886e38f)

typedef __attribute__((ext_vector_type(8))) short short8;
typedef __attribute__((ext_vector_type(4))) float f32x4;
typedef __attribute__((ext_vector_type(16))) float f32x16;
typedef unsigned short ushort_t;
typedef unsigned int uint_t;

union U16x8 { uint4 u4; ushort_t s[8]; };

static __device__ __forceinline__ ushort_t f2bf(float f) {
    uint_t u = __builtin_bit_cast(uint_t, f);
    u = (u + 0x7fff + ((u >> 16) & 1)) >> 16;
    return (ushort_t)u;
}

// async global->LDS, 16 bytes per lane (m97 pattern)
static __device__ __forceinline__ void gload_lds16(const void* g, void* l) {
    __builtin_amdgcn_global_load_lds(
        (const __attribute__((address_space(1))) unsigned int*)g,
        (__attribute__((address_space(3))) unsigned int*)l, 16, 0, 0);
}

// ---------------- LayerNorm: fp32 in -> bf16 out -----------------------------
__global__ __launch_bounds__(256) void ln_bf16_kernel(const float* __restrict__ x,
                                                      const float* __restrict__ g,
                                                      const float* __restrict__ b,
                                                      ushort_t* __restrict__ out) {
    int row = blockIdx.x;
    const float* xr = x + (size_t)row * D_;
    ushort_t* yr = out + (size_t)row * D_;
    __shared__ float red[256];
    int t = threadIdx.x;
    float vals[4];
    float s = 0.f;
#pragma unroll
    for (int i = 0; i < 4; ++i) { vals[i] = xr[t + i * 256]; s += vals[i]; }
    red[t] = s; __syncthreads();
    for (int off = 128; off > 0; off >>= 1) { if (t < off) red[t] += red[t + off]; __syncthreads(); }
    float mean = red[0] * (1.f / D_);
    __syncthreads();
    float vs = 0.f;
#pragma unroll
    for (int i = 0; i < 4; ++i) { float d = vals[i] - mean; vs += d * d; }
    red[t] = vs; __syncthreads();
    for (int off = 128; off > 0; off >>= 1) { if (t < off) red[t] += red[t + off]; __syncthreads(); }
    float rstd = 1.f / sqrtf(red[0] * (1.f / D_) + 1e-5f);
#pragma unroll
    for (int i = 0; i < 4; ++i) {
        int c = t + i * 256;
        yr[c] = f2bf((vals[i] - mean) * rstd * g[c] + b[c]);
    }
}

// ---------------- fused prep: all weight transposes + concat bias ------------
__global__ __launch_bounds__(256) void prep_kernel(
    const float* __restrict__ Wq, const float* __restrict__ Wk,
    const float* __restrict__ Wv, const float* __restrict__ Wo,
    const float* __restrict__ W1, const float* __restrict__ W2,
    const float* __restrict__ bq, const float* __restrict__ bk,
    const float* __restrict__ bv,
    ushort_t* __restrict__ qkvT, ushort_t* __restrict__ WoT,
    ushort_t* __restrict__ W1T, ushort_t* __restrict__ W2T,
    float* __restrict__ cb)
{
    int id = blockIdx.x;
    if (id >= 12288) {
        int i = (id - 12288) * 256 + threadIdx.x;
        cb[i] = (i < 1024) ? bq[i] : ((i < 2048) ? bk[i - 1024] : bv[i - 2048]);
        return;
    }
    const float* in; ushort_t* outp; int K, N, tid;
    if (id < 4096) {
        int wsel = id >> 10; tid = id & 1023; K = D_; N = D_;
        in   = (wsel == 0) ? Wq : (wsel == 1) ? Wk : (wsel == 2) ? Wv : Wo;
        outp = (wsel == 0) ? qkvT : (wsel == 1) ? qkvT + 1024 * 1024
             : (wsel == 2) ? qkvT + 2 * 1024 * 1024 : WoT;
    } else if (id < 8192) { tid = id - 4096; K = D_; N = 4 * D_; in = W1; outp = W1T; }
    else                  { tid = id - 8192; K = 4 * D_; N = D_; in = W2; outp = W2T; }
    int tilesX = N >> 5;
    int n0 = (tid % tilesX) * 32, k0 = (tid / tilesX) * 32;

    __shared__ float tile[32][33];
    int tx = threadIdx.x & 31, ty = threadIdx.x >> 5;   // ty 0..7
#pragma unroll
    for (int r = 0; r < 4; ++r)
        tile[ty + r * 8][tx] = in[(size_t)(k0 + ty + r * 8) * N + n0 + tx];
    __syncthreads();
#pragma unroll
    for (int r = 0; r < 4; ++r)
        outp[(size_t)(n0 + ty + r * 8) * K + k0 + tx] = f2bf(tile[tx][ty + r * 8]);
}

// ---------------- edge-bias projection: eb[b,e,h] ----------------------------
__global__ __launch_bounds__(256) void eb_kernel(const float* __restrict__ re,
                                                 const float* __restrict__ We,
                                                 const float* __restrict__ be,
                                                 float* __restrict__ eb) {
    __shared__ float rs[16 * 256];
    __shared__ float wl[256 * 16];
    int t = threadIdx.x;
    int be0 = blockIdx.x * 16;     // base (b*E+e)
#pragma unroll
    for (int i = 0; i < 16; ++i) wl[t + i * 256] = We[t + i * 256];
#pragma unroll
    for (int i = 0; i < 16; ++i) rs[t + i * 256] = re[(size_t)be0 * 256 + t + i * 256];
    __syncthreads();
    int el = t >> 4, h = t & 15;
    float s = be[h];
#pragma unroll 8
    for (int i = 0; i < 256; ++i) s += rs[el * 256 + i] * wl[i * 16 + h];
    eb[(size_t)(be0 + el) * 16 + h] = s;
}

// ---------------- edge scatter: last-writer-wins priority table --------------
__global__ void scatter_kernel(const int* __restrict__ edges, const float* __restrict__ emask,
                               int* __restrict__ prio) {
    int idx = blockIdx.x * blockDim.x + threadIdx.x;   // b*E + e
    if (idx >= B_ * E_) return;
    if (emask[idx] == 0.f) return;
    int b = idx / E_, e = idx % E_;
    int s = edges[2 * idx], d = edges[2 * idx + 1];
    s = min(max(s, 0), N_ - 1);
    d = min(max(d, 0), N_ - 1);
    int* base = prio + (size_t)b * N_ * N_;
    atomicMax(&base[s * N_ + d], e);
    atomicMax(&base[d * N_ + s], e + E_);
}

// ---------------- bf16 MFMA GEMM, BK=64 (modes 0,2) --------------------------
// 128x128 block, 4 waves in 2x2, wave 64x64. R6 supertile + row&7 XOR swizzle.
template<int MODE>
__global__ __launch_bounds__(256) void gemm_bf16(
    const ushort_t* __restrict__ A, const ushort_t* __restrict__ BT,
    const float* __restrict__ bias, const float* __restrict__ res,
    const float* __restrict__ nm, void* __restrict__ Cout,
    int M, int N, int K)
{
    __shared__ ushort_t As[128 * 64];   // 16 KB
    __shared__ ushort_t Bs[128 * 64];   // 16 KB
    int t = threadIdx.x;
    int lane = t & 63;
    int l31 = lane & 31, lh = lane >> 5;
    int w = t >> 6;
    int wr = (w >> 1) * 64, wc = (w & 1) * 64;

    int bid = blockIdx.x;
    int xcd = bid & 7;
    int lid = bid >> 3;
    int st  = lid >> 5;
    int ls  = lid & 31;
    int brow = xcd * 8 + (ls >> 2);
    int bcol = st * 4 + (ls & 3);
    int row0 = brow * 128, col0 = bcol * 128;

    const ushort_t* Ag = A + (size_t)row0 * K;
    const ushort_t* Bg = BT + (size_t)col0 * K;
    int srow = t >> 3;                             // 0..31
    int slot = t & 7;
    int sc = (slot ^ (srow & 7)) * 8;

    f32x16 acc[2][2];
#pragma unroll
    for (int i = 0; i < 2; ++i)
#pragma unroll
        for (int j = 0; j < 2; ++j)
#pragma unroll
            for (int r = 0; r < 16; ++r) acc[i][j][r] = 0.f;

    for (int k0 = 0; k0 < K; k0 += 64) {
#pragma unroll
        for (int i = 0; i < 4; ++i) {
            gload_lds16(Ag + (size_t)(i * 32 + srow) * K + k0 + sc, (char*)As + i * 4096 + t * 16);
            gload_lds16(Bg + (size_t)(i * 32 + srow) * K + k0 + sc, (char*)Bs + i * 4096 + t * 16);
        }
        __syncthreads();
#pragma unroll
        for (int ks = 0; ks < 4; ++ks) {
            short8 af[2], bfr[2];
#pragma unroll
            for (int it = 0; it < 2; ++it) {
                int m = wr + it * 32 + l31;
                int x = ((ks * 2 + lh) ^ (m & 7)) * 16;
                af[it] = *(const short8*)((const char*)As + m * 128 + x);
            }
#pragma unroll
            for (int jt = 0; jt < 2; ++jt) {
                int n = wc + jt * 32 + l31;
                int x = ((ks * 2 + lh) ^ (n & 7)) * 16;
                bfr[jt] = *(const short8*)((const char*)Bs + n * 128 + x);
            }
#pragma unroll
            for (int it = 0; it < 2; ++it)
#pragma unroll
                for (int jt = 0; jt < 2; ++jt)
                    acc[it][jt] = __builtin_amdgcn_mfma_f32_32x32x16_bf16(af[it], bfr[jt], acc[it][jt], 0, 0, 0);
        }
        __syncthreads();
    }

#pragma unroll
    for (int it = 0; it < 2; ++it) {
#pragma unroll
        for (int jt = 0; jt < 2; ++jt) {
            int col = col0 + wc + jt * 32 + l31;
            float bcol_b = bias[col];
#pragma unroll
            for (int reg = 0; reg < 16; ++reg) {
                int row = row0 + wr + it * 32 + (reg & 3) + 8 * (reg >> 2) + 4 * lh;
                float v = acc[it][jt][reg] + bcol_b;
                if (MODE == 0) {
                    ((ushort_t*)Cout)[(size_t)row * N + col] = f2bf(v);
                } else { // 2
                    v = v / (1.f + __expf(-v));
                    ((ushort_t*)Cout)[(size_t)row * N + col] = f2bf(v);
                }
            }
        }
    }
}

// ---------------- bf16 MFMA GEMM, BK=128 (modes 1,3 — grid-capped) -----------
template<int MODE>
__global__ __launch_bounds__(256) void gemm_res(
    const ushort_t* __restrict__ A, const ushort_t* __restrict__ BT,
    const float* __restrict__ bias, const float* __restrict__ res,
    const float* __restrict__ nm, void* __restrict__ Cout,
    int M, int N, int K)
{
    __shared__ ushort_t As[2][128 * 64];   // 32 KB
    __shared__ ushort_t Bs[2][128 * 64];   // 32 KB
    int t = threadIdx.x;
    int lane = t & 63;
    int l31 = lane & 31, lh = lane >> 5;
    int w = t >> 6;
    int wr = (w >> 1) * 64, wc = (w & 1) * 64;

    int bid = blockIdx.x;
    int xcd = bid & 7;
    int lid = bid >> 3;
    int st  = lid >> 5;
    int ls  = lid & 31;
    int brow = xcd * 8 + (ls >> 2);
    int bcol = st * 4 + (ls & 3);
    int row0 = brow * 128, col0 = bcol * 128;

    const ushort_t* Ag = A + (size_t)row0 * K;
    const ushort_t* Bg = BT + (size_t)col0 * K;
    int srow = t >> 3;
    int slot = t & 7;
    int sc = (slot ^ (srow & 7)) * 8;

    f32x16 acc[2][2];
#pragma unroll
    for (int i = 0; i < 2; ++i)
#pragma unroll
        for (int j = 0; j < 2; ++j)
#pragma unroll
            for (int r = 0; r < 16; ++r) acc[i][j][r] = 0.f;

    for (int k0 = 0; k0 < K; k0 += 128) {
#pragma unroll
        for (int p = 0; p < 2; ++p)
#pragma unroll
            for (int i = 0; i < 4; ++i) {
                gload_lds16(Ag + (size_t)(i * 32 + srow) * K + k0 + p * 64 + sc,
                            (char*)As + p * 16384 + i * 4096 + t * 16);
                gload_lds16(Bg + (size_t)(i * 32 + srow) * K + k0 + p * 64 + sc,
                            (char*)Bs + p * 16384 + i * 4096 + t * 16);
            }
        __syncthreads();
#pragma unroll
        for (int ks8 = 0; ks8 < 8; ++ks8) {
            const char* Ab = (const char*)As + (ks8 >> 2) * 16384;
            const char* Bb = (const char*)Bs + (ks8 >> 2) * 16384;
            int kk = ks8 & 3;
            short8 af[2], bfr[2];
#pragma unroll
            for (int it = 0; it < 2; ++it) {
                int m = wr + it * 32 + l31;
                int x = ((kk * 2 + lh) ^ (m & 7)) * 16;
                af[it] = *(const short8*)(Ab + m * 128 + x);
            }
#pragma unroll
            for (int jt = 0; jt < 2; ++jt) {
                int n = wc + jt * 32 + l31;
                int x = ((kk * 2 + lh) ^ (n & 7)) * 16;
                bfr[jt] = *(const short8*)(Bb + n * 128 + x);
            }
#pragma unroll
            for (int it = 0; it < 2; ++it)
#pragma unroll
                for (int jt = 0; jt < 2; ++jt)
                    acc[it][jt] = __builtin_amdgcn_mfma_f32_32x32x16_bf16(af[it], bfr[jt], acc[it][jt], 0, 0, 0);
        }
        __syncthreads();
    }

#pragma unroll
    for (int it = 0; it < 2; ++it) {
#pragma unroll
        for (int jt = 0; jt < 2; ++jt) {
            int col = col0 + wc + jt * 32 + l31;
            float bcol_b = bias[col];
#pragma unroll
            for (int reg = 0; reg < 16; ++reg) {
                int row = row0 + wr + it * 32 + (reg & 3) + 8 * (reg >> 2) + 4 * lh;
                float v = acc[it][jt][reg] + bcol_b;
                if (MODE == 1) {
                    ((float*)Cout)[(size_t)row * N + col] = v + res[(size_t)row * N + col];
                } else { // 3
                    v = (v + res[(size_t)row * N + col]) * nm[row];
                    ((float*)Cout)[(size_t)row * N + col] = v;
                }
            }
        }
    }
}

// ---------------- 256x256 8-phase GEMM (mode 2, m201 stagger) ----------------
template<int NBN>
__global__ __launch_bounds__(512) void gemm256(
    const ushort_t* __restrict__ A, const ushort_t* __restrict__ BT,
    const float* __restrict__ bias, ushort_t* __restrict__ Cout,
    int M, int N, int K)
{
    __shared__ ushort_t As[2][2][128 * 64];   // 64 KB
    __shared__ ushort_t Bs[2][2][128 * 64];   // 64 KB

    int t = threadIdx.x;
    int lane = t & 63;
    int w = t >> 6;                 // 0..7
    int wm = w >> 2, wn = w & 3;    // 2M x 4N
    int c2 = lane & 15, quad = lane >> 4;

    int bid = blockIdx.x;
    int xcd = bid & 7, lid = bid >> 3;          // 64 per XCD
    int brow = xcd * 4 + (lid & 3);             // brow fastest within XCD
    int bcol = lid >> 2;
    int row0 = brow * 256, col0 = bcol * 256;

    const ushort_t* Ag = A + (size_t)row0 * K;
    const ushort_t* Bg = BT + (size_t)col0 * K;

    int srow = t >> 3, slot = t & 7;            // srow 0..63
    int sc = (slot ^ (srow & 7)) * 8;           // source chunk (elems)

    // hh: 0=A half0, 1=A half1, 2=B half0, 3=B half1 ; one half = 2 gloads
    auto stage = [&](int buf, int hh, int kt) {
        const ushort_t* g = (hh < 2) ? Ag : Bg;
        int h = hh & 1;
        char* l = (hh < 2) ? (char*)&As[buf][h][0] : (char*)&Bs[buf][h][0];
        gload_lds16(g + (size_t)(h * 128 + srow) * K + kt * 64 + sc, l + t * 16);
        gload_lds16(g + (size_t)(h * 128 + 64 + srow) * K + kt * 64 + sc, l + 8192 + t * 16);
    };

    f32x4 acc[8][4];
#pragma unroll
    for (int a_ = 0; a_ < 8; ++a_)
#pragma unroll
        for (int b_ = 0; b_ < 4; ++b_)
#pragma unroll
            for (int r = 0; r < 4; ++r) acc[a_][b_][r] = 0.f;

    int T = K >> 6;
    // prologue: tile0 {A0,A1,B0,B1}, tile1 {B0,B1,A0}  (age order matters)
    stage(0, 0, 0); stage(0, 1, 0); stage(0, 2, 0); stage(0, 3, 0);
    if (T > 1) { stage(1, 2, 1); stage(1, 3, 1); stage(1, 0, 1); }

    const int bhalf = wn >> 1, bco = (wn & 1) * 64;

    for (int tau = 0; tau < T; ++tau) {
        int bc = tau & 1;
        const char* Ab = (const char*)&As[bc][wm][0];
        const char* Bb = (const char*)&Bs[bc][bhalf][0];
        short8 bfr[4][2];
#pragma unroll
        for (int q = 0; q < 4; ++q) {
            if (q == 0) {
                if (tau == T - 1) asm volatile("s_waitcnt vmcnt(0)" ::: "memory");
                else              asm volatile("s_waitcnt vmcnt(6)" ::: "memory");
                __builtin_amdgcn_s_barrier();
                __builtin_amdgcn_sched_barrier(0);
            }
            short8 afr[2][2];
#pragma unroll
            for (int it = 0; it < 2; ++it)
#pragma unroll
                for (int ks = 0; ks < 2; ++ks) {
                    int fr = q * 32 + it * 16 + c2;
                    afr[it][ks] = *(const short8*)(Ab + fr * 128 + (((ks * 4 + quad) ^ (fr & 7)) * 16));
                }
            if (q == 0) {
#pragma unroll
                for (int jt = 0; jt < 4; ++jt)
#pragma unroll
                    for (int ks = 0; ks < 2; ++ks) {
                        int fr = bco + jt * 16 + c2;
                        bfr[jt][ks] = *(const short8*)(Bb + fr * 128 + (((ks * 4 + quad) ^ (fr & 7)) * 16));
                    }
            }
            // staggered staging slot
            if (q == 0) { if (tau + 1 < T) stage(bc ^ 1, 1, tau + 1); }
            else if (tau + 2 < T) stage(bc, (q == 1) ? 2 : (q == 2) ? 3 : 0, tau + 2);

            asm volatile("s_waitcnt lgkmcnt(0)" ::: "memory");
            __builtin_amdgcn_sched_barrier(0);
            __builtin_amdgcn_s_setprio(1);
#pragma unroll
            for (int it = 0; it < 2; ++it)
#pragma unroll
                for (int jt = 0; jt < 4; ++jt) {
                    acc[q * 2 + it][jt] = __builtin_amdgcn_mfma_f32_16x16x32_bf16(
                        afr[it][0], bfr[jt][0], acc[q * 2 + it][jt], 0, 0, 0);
                    acc[q * 2 + it][jt] = __builtin_amdgcn_mfma_f32_16x16x32_bf16(
                        afr[it][1], bfr[jt][1], acc[q * 2 + it][jt], 0, 0, 0);
                }
            __builtin_amdgcn_s_setprio(0);
            __builtin_amdgcn_sched_barrier(0);
            __builtin_amdgcn_s_barrier();
        }
    }

    // epilogue: 16x16 C/D layout (m89): row = quad*4 + r, col = c2 ; silu+bf16
#pragma unroll
    for (int q = 0; q < 4; ++q)
#pragma unroll
        for (int it = 0; it < 2; ++it) {
            int row = row0 + wm * 128 + q * 32 + it * 16 + quad * 4;
#pragma unroll
            for (int jt = 0; jt < 4; ++jt) {
                int col = col0 + wn * 64 + jt * 16 + c2;
                float bc_ = bias[col];
#pragma unroll
                for (int r = 0; r < 4; ++r) {
                    float v = acc[q * 2 + it][jt][r] + bc_;
                    v = v / (1.f + __expf(-v));
                    Cout[(size_t)(row + r) * N + col] = f2bf(v);
                }
            }
        }
}

// ---------------- MFMA attention: block = (b, h, q-tile of 64) ---------------
__global__ __launch_bounds__(256, 2) void attn_mfma_kernel(
    const ushort_t* __restrict__ qkv, const int* __restrict__ prio,
    const float* __restrict__ eb, const float* __restrict__ nm,
    ushort_t* __restrict__ out)
{
    int xb = blockIdx.x;
    int bid = (xb & 7) * 256 + (xb >> 3);
    int h = bid & 15, qt = (bid >> 4) & 3, b = bid >> 6;
    int t = threadIdx.x;

    __shared__ ushort_t Ks[256 * 72];
    __shared__ ushort_t Vt[64 * 264];

    int lane = t & 63, c = lane & 15, quad = lane >> 4;
    int w = t >> 6;
    int qbase = qt * 64 + w * 16 + quad * 4;

    int pr[16][4];
    const int* prp = prio + ((size_t)(b * N_ + qbase)) * N_ + c;
#pragma unroll
    for (int j = 0; j < 16; ++j)
#pragma unroll
        for (int r = 0; r < 4; ++r)
            pr[j][r] = prp[(size_t)r * N_ + j * 16];

    float nmq[4];
#pragma unroll
    for (int r = 0; r < 4; ++r) nmq[r] = nm[b * N_ + qbase + r];
    float nmk[16];
#pragma unroll
    for (int j = 0; j < 16; ++j) nmk[j] = nm[b * N_ + j * 16 + c];

    const ushort_t* qg = qkv + ((size_t)(b * N_ + qt * 64 + w * 16 + c)) * QS_ + h * HD_;
    short8 aq0 = *(const short8*)(const void*)(qg + quad * 8);
    short8 aq1 = *(const short8*)(const void*)(qg + 32 + quad * 8);

    int lr = t >> 3, lc = (t & 7) * 8;
    const ushort_t* kg = qkv + ((size_t)(b * N_)) * QS_ + 1024 + h * HD_;
#pragma unroll
    for (int r = 0; r < 256; r += 32)
        *(uint4*)&Ks[(lr + r) * 72 + lc] = *(const uint4*)&kg[(size_t)(lr + r) * QS_ + lc];
    const ushort_t* vg = qkv + ((size_t)(b * N_)) * QS_ + 2048 + h * HD_;
#pragma unroll
    for (int r = 0; r < 256; r += 32) {
        U16x8 uu; uu.u4 = *(const uint4*)&vg[(size_t)(lr + r) * QS_ + lc];
#pragma unroll
        for (int i = 0; i < 8; ++i)
            Vt[(lc + i) * 264 + lr + r] = uu.s[i];
    }

    const float* ebb = eb + (size_t)b * E_ * H_ + h;
    float badd[16][4];
#pragma unroll
    for (int j = 0; j < 16; ++j) {
        int key = j * 16 + c;
#pragma unroll
        for (int r = 0; r < 4; ++r) {
            int p = pr[j][r];
            float bias = 0.f;
            bool adj = (key == qbase + r);
            if (p >= 0) {
                int e = (p >= E_) ? p - E_ : p;
                bias = ebb[(size_t)e * H_];
                adj = true;
            }
            bool ok = adj && (nmq[r] != 0.f) && (nmk[j] != 0.f);
            badd[j][r] = ok ? bias : -3.0e38f;
        }
    }
    __syncthreads();

    f32x4 z = {0.f, 0.f, 0.f, 0.f};
    f32x4 acc[16];
#pragma unroll
    for (int j = 0; j < 16; ++j) acc[j] = z;
    __builtin_amdgcn_s_setprio(1);
#pragma unroll
    for (int j = 0; j < 16; ++j) {
        short8 b0 = *(const short8*)(const void*)(Ks + (j * 16 + c) * 72 + quad * 8);
        short8 b1 = *(const short8*)(const void*)(Ks + (j * 16 + c) * 72 + 32 + quad * 8);
        acc[j] = __builtin_amdgcn_mfma_f32_16x16x32_bf16(aq0, b0, acc[j], 0, 0, 0);
        acc[j] = __builtin_amdgcn_mfma_f32_16x16x32_bf16(aq1, b1, acc[j], 0, 0, 0);
    }
    __builtin_amdgcn_s_setprio(0);

#pragma unroll
    for (int j = 0; j < 16; ++j)
#pragma unroll
        for (int r = 0; r < 4; ++r)
            acc[j][r] = acc[j][r] * 0.125f + badd[j][r];

    float inv[4];
#pragma unroll
    for (int r = 0; r < 4; ++r) {
        float m = acc[0][r];
#pragma unroll
        for (int j = 1; j < 16; ++j) m = fmaxf(m, acc[j][r]);
        m = fmaxf(m, __shfl_xor(m, 1));
        m = fmaxf(m, __shfl_xor(m, 2));
        m = fmaxf(m, __shfl_xor(m, 4));
        m = fmaxf(m, __shfl_xor(m, 8));
        float s = 0.f;
#pragma unroll
        for (int j = 0; j < 16; ++j) {
            float p = __expf(acc[j][r] - m);
            acc[j][r] = p;
            s += p;
        }
        s += __shfl_xor(s, 1);
        s += __shfl_xor(s, 2);
        s += __shfl_xor(s, 4);
        s += __shfl_xor(s, 8);
        inv[r] = 1.f / s;
    }

    __syncthreads();
    ushort_t* Ps = Ks;
#pragma unroll
    for (int j = 0; j < 16; ++j)
#pragma unroll
        for (int r = 0; r < 4; ++r)
            Ps[(w * 16 + quad * 4 + r) * 264 + j * 16 + c] = f2bf(acc[j][r] * inv[r]);
    asm volatile("s_waitcnt lgkmcnt(0)" ::: "memory");

    f32x4 oc[4];
#pragma unroll
    for (int dt = 0; dt < 4; ++dt) oc[dt] = z;
    __builtin_amdgcn_s_setprio(1);
#pragma unroll
    for (int k0 = 0; k0 < 256; k0 += 32) {
        short8 ap = *(const short8*)(const void*)(Ps + (w * 16 + c) * 264 + k0 + quad * 8);
#pragma unroll
        for (int dt = 0; dt < 4; ++dt) {
            short8 bv = *(const short8*)(const void*)(Vt + (dt * 16 + c) * 264 + k0 + quad * 8);
            oc[dt] = __builtin_amdgcn_mfma_f32_16x16x32_bf16(ap, bv, oc[dt], 0, 0, 0);
        }
    }
    __builtin_amdgcn_s_setprio(0);
    ushort_t* og = out + ((size_t)(b * N_ + qt * 64 + w * 16)) * D_ + h * HD_;
#pragma unroll
    for (int dt = 0; dt < 4; ++dt)
#pragma unroll
        for (int r = 0; r < 4; ++r)
            og[(size_t)(quad * 4 + r) * D_ + dt * 16 + c] = f2bf(oc[dt][r]);
}

extern "C" void kernel_launch(void* const* d_in, const int* in_sizes, int n_in,
                              void* d_out, int out_size, void* d_ws, size_t ws_size,
                              hipStream_t stream) {
    const float* x     = (const float*)d_in[0];
    const float* nm    = (const float*)d_in[1];
    const int*   edges = (const int*)d_in[2];
    const float* emask = (const float*)d_in[3];
    const float* remb  = (const float*)d_in[4];
    const float* ln_g  = (const float*)d_in[5];
    const float* ln_b  = (const float*)d_in[6];
    const float* Wq = (const float*)d_in[7];  const float* bq = (const float*)d_in[8];
    const float* Wk = (const float*)d_in[9];  const float* bk = (const float*)d_in[10];
    const float* Wv = (const float*)d_in[11]; const float* bv = (const float*)d_in[12];
    const float* We = (const float*)d_in[13]; const float* be = (const float*)d_in[14];
    const float* Wo = (const float*)d_in[15]; const float* bo = (const float*)d_in[16];
    const float* ff_g = (const float*)d_in[17]; const float* ff_b = (const float*)d_in[18];
    const float* W1 = (const float*)d_in[19]; const float* b1 = (const float*)d_in[20];
    const float* W2 = (const float*)d_in[21]; const float* b2 = (const float*)d_in[22];
    float* out = (float*)d_out;

    char* ws = (char*)d_ws;
    const size_t MB = 1ll << 20;
    int*      prio = (int*)ws;                       // 0..8 MB
    float*    ebuf = (float*)(ws + 8 * MB);          // 8..9 MB
    ushort_t* xn   = (ushort_t*)(ws + 9 * MB);       // 9..25 MB (reused: attn_out)
    float*    x2   = (float*)(ws + 25 * MB);         // 25..57 MB
    ushort_t* hn   = (ushort_t*)(ws + 57 * MB);      // 57..73 MB
    ushort_t* qkv  = (ushort_t*)(ws + 73 * MB);      // 73..121 MB [8192][3072]
    ushort_t* mid  = qkv;                            // 73..137 MB (qkv dead by then)
    ushort_t* qkvT = (ushort_t*)(ws + 137 * MB);     // 137..143 MB [3072][1024]
    ushort_t* WoT  = (ushort_t*)(ws + 143 * MB);     // 143..145 MB
    ushort_t* W1T  = (ushort_t*)(ws + 145 * MB);     // 145..153 MB [4096][1024]
    ushort_t* W2T  = (ushort_t*)(ws + 153 * MB);     // 153..161 MB [1024][4096]
    float*    cb   = (float*)(ws + 161 * MB);        // 161..161.02 MB [3072]
    ushort_t* aout = xn;

    const int M = B_ * N_;   // 8192

    (void)hipMemsetAsync(prio, 0xFF, (size_t)B_ * N_ * N_ * sizeof(int), stream);
    eb_kernel<<<B_ * E_ / 16, 256, 0, stream>>>(remb, We, be, ebuf);
    scatter_kernel<<<(B_ * E_ + 255) / 256, 256, 0, stream>>>(edges, emask, prio);

    prep_kernel<<<12300, 256, 0, stream>>>(Wq, Wk, Wv, Wo, W1, W2, bq, bk, bv,
                                           qkvT, WoT, W1T, W2T, cb);

    ln_bf16_kernel<<<M, 256, 0, stream>>>(x, ln_g, ln_b, xn);

    gemm_bf16<0><<<24 * 64, 256, 0, stream>>>(xn, qkvT, cb, nullptr, nullptr, qkv, M, QS_, D_);

    attn_mfma_kernel<<<B_ * H_ * 4, 256, 0, stream>>>(qkv, prio, ebuf, nm, aout);

    gemm_res<1><<<8 * 64, 256, 0, stream>>>(aout, WoT, bo, x, nullptr, x2, M, D_, D_);
    ln_bf16_kernel<<<M, 256, 0, stream>>>(x2, ff_g, ff_b, hn);

    // FFN up: 256x256 8-phase (m201 stagger), grid 512 = 2 rounds @ 1 block/CU
    gemm256<16><<<512, 512, 0, stream>>>(hn, W1T, b1, mid, M, 4 * D_, D_);
    // FFN down: BK=128, grid-capped 512 blocks (best measured structure)
    gemm_res<3><<<8 * 64, 256, 0, stream>>>(mid, W2T, b2, x2, nm, out, M, D_, 4 * D_);
}